// Round 1
// baseline (523.021 us; speedup 1.0000x reference)
//
#include <hip/hip_runtime.h>

#define Bn 64
#define Cn 8
#define Hn 256
#define Wn 256
#define HWn 65536
#define CHWn 524288

// ---------------------------------------------------------------- K1: q,k
// q[b,i,w] = sum_c x[b,c,i,w]*w1[c] + b1 ; same for k with w2,b2.
__global__ __launch_bounds__(256) void qk_kernel(
    const float* __restrict__ x, const float* __restrict__ w1, const float* __restrict__ b1,
    const float* __restrict__ w2, const float* __restrict__ b2,
    float* __restrict__ q, float* __restrict__ k) {
  int n = blockIdx.x * 256 + threadIdx.x;   // 0 .. B*H*W-1
  int b = n >> 16;
  int p = n & 65535;
  const float* xb = x + (size_t)b * CHWn + p;
  float qa = b1[0], ka = b2[0];
#pragma unroll
  for (int c = 0; c < Cn; c++) {
    float xv = xb[c * HWn];
    qa = fmaf(xv, w1[c], qa);
    ka = fmaf(xv, w2[c], ka);
  }
  q[n] = qa;
  k[n] = ka;
}

// ---------------------------------------------------------------- K2: scores = q @ k^T  (per batch, 256x256x256)
// 128x128 tile per block, 256 threads, 8x8 microtile split as (4+4)x(4+4).
// LDS tiles transposed [w][i], stride 132 so float4 reads are 16B-aligned and <=2-way bank aliased.
__global__ __launch_bounds__(256) void scores_kernel(
    const float* __restrict__ q, const float* __restrict__ k, float* __restrict__ sc) {
  const int jt = blockIdx.x, it = blockIdx.y, b = blockIdx.z;
  const int i0 = it * 128, j0 = jt * 128;
  const int t = threadIdx.x;
  const int tx = t & 15, ty = t >> 4;
  __shared__ __align__(16) float qt[32 * 132];
  __shared__ __align__(16) float kt[32 * 132];
  float acc[2][2][4][4];
#pragma unroll
  for (int a = 0; a < 2; a++)
#pragma unroll
    for (int bb = 0; bb < 2; bb++)
#pragma unroll
      for (int il = 0; il < 4; il++)
#pragma unroll
        for (int jl = 0; jl < 4; jl++) acc[a][bb][il][jl] = 0.f;
  const float* qb = q + (size_t)b * HWn;
  const float* kb = k + (size_t)b * HWn;
  for (int kc = 0; kc < 8; kc++) {
    const int w0 = kc * 32;
    __syncthreads();  // previous chunk's readers done before overwrite
#pragma unroll
    for (int e = 0; e < 16; e++) {
      int idx = t + 256 * e;
      int r = idx >> 5, c = idx & 31;      // r: tile row 0..127, c: w 0..31
      qt[c * 132 + r] = qb[(i0 + r) * 256 + w0 + c];
      kt[c * 132 + r] = kb[(j0 + r) * 256 + w0 + c];
    }
    __syncthreads();
#pragma unroll 4
    for (int w = 0; w < 32; w++) {
      const float4 a0 = *(const float4*)&qt[w * 132 + ty * 4];
      const float4 a1 = *(const float4*)&qt[w * 132 + 64 + ty * 4];
      const float4 b0 = *(const float4*)&kt[w * 132 + tx * 4];
      const float4 b1 = *(const float4*)&kt[w * 132 + 64 + tx * 4];
      const float av[2][4] = {{a0.x, a0.y, a0.z, a0.w}, {a1.x, a1.y, a1.z, a1.w}};
      const float bv[2][4] = {{b0.x, b0.y, b0.z, b0.w}, {b1.x, b1.y, b1.z, b1.w}};
#pragma unroll
      for (int ih = 0; ih < 2; ih++)
#pragma unroll
        for (int jh = 0; jh < 2; jh++)
#pragma unroll
          for (int il = 0; il < 4; il++)
#pragma unroll
            for (int jl = 0; jl < 4; jl++)
              acc[ih][jh][il][jl] = fmaf(av[ih][il], bv[jh][jl], acc[ih][jh][il][jl]);
    }
  }
  float* scb = sc + (size_t)b * HWn;
#pragma unroll
  for (int ih = 0; ih < 2; ih++)
#pragma unroll
    for (int il = 0; il < 4; il++) {
      int i = i0 + ih * 64 + ty * 4 + il;
#pragma unroll
      for (int jh = 0; jh < 2; jh++) {
        float4 st = make_float4(acc[ih][jh][il][0], acc[ih][jh][il][1],
                                acc[ih][jh][il][2], acc[ih][jh][il][3]);
        *(float4*)&scb[i * 256 + j0 + jh * 64 + tx * 4] = st;
      }
    }
}

// ---------------------------------------------------------------- K3: softmax over last dim, in place, wave per row
__global__ __launch_bounds__(256) void softmax_kernel(float* __restrict__ at) {
  int wave = (blockIdx.x * 256 + threadIdx.x) >> 6;  // row id 0..16383
  int lane = threadIdx.x & 63;
  float* row = at + (size_t)wave * 256;
  float v[4];
  float m = -3.4e38f;
#pragma unroll
  for (int u = 0; u < 4; u++) {
    v[u] = row[lane + 64 * u];
    m = fmaxf(m, v[u]);
  }
#pragma unroll
  for (int o = 1; o < 64; o <<= 1) m = fmaxf(m, __shfl_xor(m, o, 64));
  float s = 0.f;
#pragma unroll
  for (int u = 0; u < 4; u++) {
    v[u] = __expf(v[u] - m);
    s += v[u];
  }
#pragma unroll
  for (int o = 1; o < 64; o <<= 1) s += __shfl_xor(s, o, 64);
  float inv = 1.0f / s;
#pragma unroll
  for (int u = 0; u < 4; u++) row[lane + 64 * u] = v[u] * inv;
}

// ---------------------------------------------------------------- K4: y[c,i,w] = sum_j p[i,j] x[c,j,w]; out = w3 y + b3
// block = (i-tile of 16, b); 256 threads = w. p tile staged in LDS (16KB),
// x read coalesced (L2-resident 2MB/batch), acc[8 c][16 i] in registers.
__global__ __launch_bounds__(256, 2) void apply_kernel(
    const float* __restrict__ x, const float* __restrict__ at,
    const float* __restrict__ w3, const float* __restrict__ b3, float* __restrict__ out) {
  const int it = blockIdx.x, b = blockIdx.y;
  const int i0 = it * 16;
  const int t = threadIdx.x;
  __shared__ __align__(16) float pt[16 * 256];
  const float* atb = at + (size_t)b * HWn + i0 * 256;
#pragma unroll
  for (int e = 0; e < 4; e++)
    *(float4*)&pt[t * 4 + 1024 * e] = *(const float4*)&atb[t * 4 + 1024 * e];
  __syncthreads();
  float acc[8][16];
#pragma unroll
  for (int c = 0; c < 8; c++)
#pragma unroll
    for (int ii = 0; ii < 16; ii++) acc[c][ii] = 0.f;
  const float* xb = x + (size_t)b * CHWn + t;
  for (int j0 = 0; j0 < 256; j0 += 2) {
    float p2[16][2];
#pragma unroll
    for (int ii = 0; ii < 16; ii++) {
      float2 pp = *(const float2*)&pt[ii * 256 + j0];
      p2[ii][0] = pp.x;
      p2[ii][1] = pp.y;
    }
#pragma unroll
    for (int ju = 0; ju < 2; ju++) {
      float xv[8];
#pragma unroll
      for (int c = 0; c < 8; c++) xv[c] = xb[c * HWn + (j0 + ju) * 256];
#pragma unroll
      for (int c = 0; c < 8; c++)
#pragma unroll
        for (int ii = 0; ii < 16; ii++)
          acc[c][ii] = fmaf(xv[c], p2[ii][ju], acc[c][ii]);
    }
  }
  // epilogue: 8x8 conv + bias, coalesced stores
#pragma unroll
  for (int co = 0; co < 8; co++) {
    float wr[8];
#pragma unroll
    for (int ci = 0; ci < 8; ci++) wr[ci] = w3[co * 8 + ci];
    float bb = b3[co];
#pragma unroll
    for (int ii = 0; ii < 16; ii++) {
      float o = bb;
#pragma unroll
      for (int ci = 0; ci < 8; ci++) o = fmaf(wr[ci], acc[ci][ii], o);
      out[(size_t)b * CHWn + co * HWn + (i0 + ii) * 256 + t] = o;
    }
  }
}

extern "C" void kernel_launch(void* const* d_in, const int* in_sizes, int n_in,
                              void* d_out, int out_size, void* d_ws, size_t ws_size,
                              hipStream_t stream) {
  const float* x  = (const float*)d_in[0];
  const float* w1 = (const float*)d_in[1];
  const float* b1 = (const float*)d_in[2];
  const float* w2 = (const float*)d_in[3];
  const float* b2 = (const float*)d_in[4];
  const float* w3 = (const float*)d_in[5];
  const float* b3 = (const float*)d_in[6];
  float* out = (float*)d_out;

  float* wsf = (float*)d_ws;
  float* q  = wsf;                 // 4,194,304 floats
  float* k  = wsf + 4194304;       // 4,194,304 floats
  float* at = wsf + 8388608;       // 4,194,304 floats (scores -> attn in place)
  // total ws use: 50.3 MB

  qk_kernel<<<dim3(16384), dim3(256), 0, stream>>>(x, w1, b1, w2, b2, q, k);
  scores_kernel<<<dim3(2, 2, 64), dim3(256), 0, stream>>>(q, k, at);
  softmax_kernel<<<dim3(4096), dim3(256), 0, stream>>>(at);
  apply_kernel<<<dim3(16, 64), dim3(256), 0, stream>>>(x, at, w3, b3, out);
}

// Round 2
// 390.411 us; speedup vs baseline: 1.3397x; 1.3397x over previous
//
#include <hip/hip_runtime.h>

typedef _Float16 h16;
typedef __attribute__((ext_vector_type(4))) _Float16 half4;
typedef __attribute__((ext_vector_type(8))) _Float16 half8;
typedef __attribute__((ext_vector_type(4))) float f32x4;

#define Bn 64
#define Cn 8
#define HWn 65536
#define CHWn 524288

// ================================================================ FAST PATH
// ---------------------------------------------------------------- K1: prep
// Reads x once. Produces:
//   qh,kh fp16 [b][i][w]   (i = H index)
//   xt    fp16 [b][c][w][j] (transposed H<->W, for MFMA B-operand of apply)
// LDS transpose: stride 72 halfs, XOR-16 swizzle on j by (w>>2)&3.
// Writes are half4 (4 contiguous j), reads half8 — both conflict-free.
__global__ __launch_bounds__(256) void prep_kernel(
    const float* __restrict__ x, const float* __restrict__ w1, const float* __restrict__ b1,
    const float* __restrict__ w2, const float* __restrict__ b2,
    h16* __restrict__ qh, h16* __restrict__ kh, h16* __restrict__ xt) {
  const int jt = blockIdx.x, wt = blockIdx.y, b = blockIdx.z;
  const int j0 = jt * 64, w0 = wt * 64;
  const int t = threadIdx.x;
  const int rb = 4 * (t >> 4);     // j row base within tile (4 consecutive rows)
  const int cb = 4 * (t & 15);     // w col base within tile (4 consecutive cols)
  const int sig = (t & 15) & 3;    // write swizzle = (w>>2)&3 (indep of e)
  const int wread = t >> 2;        // read phase: w row
  const int jcr = 16 * (t & 3);    // read phase: j chunk
  const int srd = (wread >> 2) & 3;
  __shared__ h16 ldsT[64 * 72];

  float qa[4][4], ka[4][4];
  const float bb1 = b1[0], bb2 = b2[0];
#pragma unroll
  for (int d = 0; d < 4; d++)
#pragma unroll
    for (int e = 0; e < 4; e++) { qa[d][e] = bb1; ka[d][e] = bb2; }

  for (int c = 0; c < Cn; c++) {
    const float* xp = x + (size_t)b * CHWn + c * HWn;
    const float w1c = w1[c], w2c = w2[c];
    float fx[4][4];
#pragma unroll
    for (int d = 0; d < 4; d++) {
      float4 xv = *(const float4*)&xp[(size_t)(j0 + rb + d) * 256 + w0 + cb];
      fx[d][0] = xv.x; fx[d][1] = xv.y; fx[d][2] = xv.z; fx[d][3] = xv.w;
      qa[d][0] = fmaf(xv.x, w1c, qa[d][0]); ka[d][0] = fmaf(xv.x, w2c, ka[d][0]);
      qa[d][1] = fmaf(xv.y, w1c, qa[d][1]); ka[d][1] = fmaf(xv.y, w2c, ka[d][1]);
      qa[d][2] = fmaf(xv.z, w1c, qa[d][2]); ka[d][2] = fmaf(xv.z, w2c, ka[d][2]);
      qa[d][3] = fmaf(xv.w, w1c, qa[d][3]); ka[d][3] = fmaf(xv.w, w2c, ka[d][3]);
    }
    // transpose into LDS: row = w (cb+e), 4 contiguous j at rb (swizzled)
#pragma unroll
    for (int e = 0; e < 4; e++) {
      half4 hv = {(h16)fx[0][e], (h16)fx[1][e], (h16)fx[2][e], (h16)fx[3][e]};
      *(half4*)&ldsT[(cb + e) * 72 + (rb ^ (16 * sig))] = hv;
    }
    __syncthreads();
    {
      const h16* src = &ldsT[wread * 72 + (jcr ^ (16 * srd))];
      half8 v0 = *(const half8*)src;
      half8 v1 = *(const half8*)(src + 8);
      h16* dst = xt + ((size_t)(b * Cn + c) * 256 + w0 + wread) * 256 + j0 + jcr;
      *(half8*)dst = v0;
      *(half8*)(dst + 8) = v1;
    }
    __syncthreads();
  }
#pragma unroll
  for (int d = 0; d < 4; d++) {
    half4 qv = {(h16)qa[d][0], (h16)qa[d][1], (h16)qa[d][2], (h16)qa[d][3]};
    half4 kv = {(h16)ka[d][0], (h16)ka[d][1], (h16)ka[d][2], (h16)ka[d][3]};
    size_t off = ((size_t)b << 16) + (size_t)(j0 + rb + d) * 256 + w0 + cb;
    *(half4*)&qh[off] = qv;
    *(half4*)&kh[off] = kv;
  }
}

// ---------------------------------------------------------------- K2: scores + softmax fused
// Block = 4 waves; wave computes rows [ib, ib+16) x all 256 j via 16 MFMA tiles,
// then in-register softmax (reduce across 16-lane groups), writes P fp16 [b][i][j].
__global__ __launch_bounds__(256) void scores_softmax_kernel(
    const h16* __restrict__ qh, const h16* __restrict__ kh, h16* __restrict__ p) {
  const int it = blockIdx.x, b = blockIdx.y;
  const int t = threadIdx.x;
  const int wv = t >> 6, lane = t & 63;
  const int m = lane & 15, quad = lane >> 4;
  const int ib = it * 64 + wv * 16;
  const h16* qrow = qh + ((size_t)b << 16) + (size_t)(ib + m) * 256 + quad * 8;
  const h16* kb   = kh + ((size_t)b << 16) + (size_t)m * 256 + quad * 8;
  f32x4 acc[16];
#pragma unroll
  for (int jt = 0; jt < 16; jt++) acc[jt] = {0.f, 0.f, 0.f, 0.f};
  for (int s = 0; s < 8; s++) {
    half8 A = *(const half8*)(qrow + s * 32);
#pragma unroll
    for (int jt = 0; jt < 16; jt++) {
      half8 B = *(const half8*)(kb + (size_t)jt * 4096 + s * 32);
      acc[jt] = __builtin_amdgcn_mfma_f32_16x16x32_f16(A, B, acc[jt], 0, 0, 0);
    }
  }
  h16* pb = p + ((size_t)b << 16);
#pragma unroll
  for (int r = 0; r < 4; r++) {
    float mx = -3.4e38f;
#pragma unroll
    for (int jt = 0; jt < 16; jt++) mx = fmaxf(mx, acc[jt][r]);
#pragma unroll
    for (int o = 1; o < 16; o <<= 1) mx = fmaxf(mx, __shfl_xor(mx, o, 64));
    float sum = 0.f;
#pragma unroll
    for (int jt = 0; jt < 16; jt++) {
      float e = __expf(acc[jt][r] - mx);
      acc[jt][r] = e;
      sum += e;
    }
#pragma unroll
    for (int o = 1; o < 16; o <<= 1) sum += __shfl_xor(sum, o, 64);
    const float inv = 1.f / sum;
    const int i = ib + quad * 4 + r;
#pragma unroll
    for (int jt = 0; jt < 16; jt++)
      pb[(size_t)i * 256 + jt * 16 + m] = (h16)(acc[jt][r] * inv);
  }
}

// ---------------------------------------------------------------- K3: apply + conv fused (MFMA)
// Y[c,i,w] = sum_j P[i,j] xt[c][w][j]; out[co] = b3 + sum_ci w3[co][ci] Y[ci].
// Wave tile: 16i x 16w x 8c (8 MFMA tiles, 32 acc VGPRs, A shared across c).
// All 8 c of a (i,w) point live in-lane -> conv in epilogue, no LDS.
// XCD swizzle: all 64 blocks of a batch land on one XCD (xt[b]=1MB stays in its L2).
__global__ __launch_bounds__(256) void apply_mfma_kernel(
    const h16* __restrict__ xt, const h16* __restrict__ p,
    const float* __restrict__ w3, const float* __restrict__ b3, float* __restrict__ out) {
  const int L = blockIdx.x;
  const int pos = L >> 3;
  const int b = (L & 7) + 8 * (pos >> 6);
  const int inner = pos & 63;
  const int it = inner >> 3, wt = inner & 7;
  const int t = threadIdx.x;
  const int wv = t >> 6, lane = t & 63;
  const int m = lane & 15, quad = lane >> 4;
  const int i0 = it * 32 + (wv >> 1) * 16;
  const int w0 = wt * 32 + (wv & 1) * 16;
  const h16* prow = p + ((size_t)b << 16) + (size_t)(i0 + m) * 256 + quad * 8;
  const h16* xb = xt + (size_t)b * Cn * HWn + (size_t)(w0 + m) * 256 + quad * 8;
  f32x4 acc[8];
#pragma unroll
  for (int c = 0; c < 8; c++) acc[c] = {0.f, 0.f, 0.f, 0.f};
  for (int s = 0; s < 8; s++) {
    half8 A = *(const half8*)(prow + s * 32);
#pragma unroll
    for (int c = 0; c < 8; c++) {
      half8 B = *(const half8*)(xb + (size_t)c * HWn + s * 32);
      acc[c] = __builtin_amdgcn_mfma_f32_16x16x32_f16(A, B, acc[c], 0, 0, 0);
    }
  }
  float* ob = out + (size_t)b * CHWn;
#pragma unroll
  for (int r = 0; r < 4; r++) {
    const int i = i0 + quad * 4 + r;
#pragma unroll
    for (int co = 0; co < 8; co++) {
      float o = b3[co];
#pragma unroll
      for (int ci = 0; ci < 8; ci++) o = fmaf(w3[co * 8 + ci], acc[ci][r], o);
      ob[(size_t)co * HWn + (size_t)i * 256 + w0 + m] = o;
    }
  }
}

// ================================================================ FALLBACK (fp32, R1-proven) — used only if ws too small
__global__ __launch_bounds__(256) void qk_kernel(
    const float* __restrict__ x, const float* __restrict__ w1, const float* __restrict__ b1,
    const float* __restrict__ w2, const float* __restrict__ b2,
    float* __restrict__ q, float* __restrict__ k) {
  int n = blockIdx.x * 256 + threadIdx.x;
  int b = n >> 16;
  int pidx = n & 65535;
  const float* xb = x + (size_t)b * CHWn + pidx;
  float qa = b1[0], ka = b2[0];
#pragma unroll
  for (int c = 0; c < Cn; c++) {
    float xv = xb[c * HWn];
    qa = fmaf(xv, w1[c], qa);
    ka = fmaf(xv, w2[c], ka);
  }
  q[n] = qa;
  k[n] = ka;
}

__global__ __launch_bounds__(256) void scores_kernel(
    const float* __restrict__ q, const float* __restrict__ k, float* __restrict__ sc) {
  const int jt = blockIdx.x, it = blockIdx.y, b = blockIdx.z;
  const int i0 = it * 128, j0 = jt * 128;
  const int t = threadIdx.x;
  const int tx = t & 15, ty = t >> 4;
  __shared__ __align__(16) float qt[32 * 132];
  __shared__ __align__(16) float kt[32 * 132];
  float acc[2][2][4][4];
#pragma unroll
  for (int a = 0; a < 2; a++)
#pragma unroll
    for (int bb = 0; bb < 2; bb++)
#pragma unroll
      for (int il = 0; il < 4; il++)
#pragma unroll
        for (int jl = 0; jl < 4; jl++) acc[a][bb][il][jl] = 0.f;
  const float* qb = q + (size_t)b * HWn;
  const float* kb = k + (size_t)b * HWn;
  for (int kc = 0; kc < 8; kc++) {
    const int w0 = kc * 32;
    __syncthreads();
#pragma unroll
    for (int e = 0; e < 16; e++) {
      int idx = t + 256 * e;
      int r = idx >> 5, c = idx & 31;
      qt[c * 132 + r] = qb[(i0 + r) * 256 + w0 + c];
      kt[c * 132 + r] = kb[(j0 + r) * 256 + w0 + c];
    }
    __syncthreads();
#pragma unroll 4
    for (int w = 0; w < 32; w++) {
      const float4 a0 = *(const float4*)&qt[w * 132 + ty * 4];
      const float4 a1 = *(const float4*)&qt[w * 132 + 64 + ty * 4];
      const float4 b0 = *(const float4*)&kt[w * 132 + tx * 4];
      const float4 b1 = *(const float4*)&kt[w * 132 + 64 + tx * 4];
      const float av[2][4] = {{a0.x, a0.y, a0.z, a0.w}, {a1.x, a1.y, a1.z, a1.w}};
      const float bv[2][4] = {{b0.x, b0.y, b0.z, b0.w}, {b1.x, b1.y, b1.z, b1.w}};
#pragma unroll
      for (int ih = 0; ih < 2; ih++)
#pragma unroll
        for (int jh = 0; jh < 2; jh++)
#pragma unroll
          for (int il = 0; il < 4; il++)
#pragma unroll
            for (int jl = 0; jl < 4; jl++)
              acc[ih][jh][il][jl] = fmaf(av[ih][il], bv[jh][jl], acc[ih][jh][il][jl]);
    }
  }
  float* scb = sc + (size_t)b * HWn;
#pragma unroll
  for (int ih = 0; ih < 2; ih++)
#pragma unroll
    for (int il = 0; il < 4; il++) {
      int i = i0 + ih * 64 + ty * 4 + il;
#pragma unroll
      for (int jh = 0; jh < 2; jh++) {
        float4 st = make_float4(acc[ih][jh][il][0], acc[ih][jh][il][1],
                                acc[ih][jh][il][2], acc[ih][jh][il][3]);
        *(float4*)&scb[i * 256 + j0 + jh * 64 + tx * 4] = st;
      }
    }
}

__global__ __launch_bounds__(256) void softmax_kernel(float* __restrict__ at) {
  int wave = (blockIdx.x * 256 + threadIdx.x) >> 6;
  int lane = threadIdx.x & 63;
  float* row = at + (size_t)wave * 256;
  float v[4];
  float mm = -3.4e38f;
#pragma unroll
  for (int u = 0; u < 4; u++) {
    v[u] = row[lane + 64 * u];
    mm = fmaxf(mm, v[u]);
  }
#pragma unroll
  for (int o = 1; o < 64; o <<= 1) mm = fmaxf(mm, __shfl_xor(mm, o, 64));
  float s = 0.f;
#pragma unroll
  for (int u = 0; u < 4; u++) {
    v[u] = __expf(v[u] - mm);
    s += v[u];
  }
#pragma unroll
  for (int o = 1; o < 64; o <<= 1) s += __shfl_xor(s, o, 64);
  float inv = 1.0f / s;
#pragma unroll
  for (int u = 0; u < 4; u++) row[lane + 64 * u] = v[u] * inv;
}

__global__ __launch_bounds__(256, 2) void apply_kernel(
    const float* __restrict__ x, const float* __restrict__ at,
    const float* __restrict__ w3, const float* __restrict__ b3, float* __restrict__ out) {
  const int it = blockIdx.x, b = blockIdx.y;
  const int i0 = it * 16;
  const int t = threadIdx.x;
  __shared__ __align__(16) float pt[16 * 256];
  const float* atb = at + (size_t)b * HWn + i0 * 256;
#pragma unroll
  for (int e = 0; e < 4; e++)
    *(float4*)&pt[t * 4 + 1024 * e] = *(const float4*)&atb[t * 4 + 1024 * e];
  __syncthreads();
  float acc[8][16];
#pragma unroll
  for (int c = 0; c < 8; c++)
#pragma unroll
    for (int ii = 0; ii < 16; ii++) acc[c][ii] = 0.f;
  const float* xb = x + (size_t)b * CHWn + t;
  for (int j0 = 0; j0 < 256; j0 += 2) {
    float p2[16][2];
#pragma unroll
    for (int ii = 0; ii < 16; ii++) {
      float2 pp = *(const float2*)&pt[ii * 256 + j0];
      p2[ii][0] = pp.x;
      p2[ii][1] = pp.y;
    }
#pragma unroll
    for (int ju = 0; ju < 2; ju++) {
      float xv[8];
#pragma unroll
      for (int c = 0; c < 8; c++) xv[c] = xb[c * HWn + (j0 + ju) * 256];
#pragma unroll
      for (int c = 0; c < 8; c++)
#pragma unroll
        for (int ii = 0; ii < 16; ii++)
          acc[c][ii] = fmaf(xv[c], p2[ii][ju], acc[c][ii]);
    }
  }
#pragma unroll
  for (int co = 0; co < 8; co++) {
    float wr[8];
#pragma unroll
    for (int ci = 0; ci < 8; ci++) wr[ci] = w3[co * 8 + ci];
    float bb = b3[co];
#pragma unroll
    for (int ii = 0; ii < 16; ii++) {
      float o = bb;
#pragma unroll
      for (int ci = 0; ci < 8; ci++) o = fmaf(wr[ci], acc[ci][ii], o);
      out[(size_t)b * CHWn + co * HWn + (i0 + ii) * 256 + t] = o;
    }
  }
}

extern "C" void kernel_launch(void* const* d_in, const int* in_sizes, int n_in,
                              void* d_out, int out_size, void* d_ws, size_t ws_size,
                              hipStream_t stream) {
  const float* x  = (const float*)d_in[0];
  const float* w1 = (const float*)d_in[1];
  const float* b1 = (const float*)d_in[2];
  const float* w2 = (const float*)d_in[3];
  const float* b2 = (const float*)d_in[4];
  const float* w3 = (const float*)d_in[5];
  const float* b3 = (const float*)d_in[6];
  float* out = (float*)d_out;

  if (ws_size >= (size_t)92274688) {
    // fast path: xt 64MB | qh 8MB | kh 8MB | p 8MB
    char* wsb = (char*)d_ws;
    h16* xt = (h16*)wsb;
    h16* qh = (h16*)(wsb + 67108864);
    h16* kh = (h16*)(wsb + 75497472);
    h16* p  = (h16*)(wsb + 83886080);
    prep_kernel<<<dim3(4, 4, 64), dim3(256), 0, stream>>>(x, w1, b1, w2, b2, qh, kh, xt);
    scores_softmax_kernel<<<dim3(4, 64), dim3(256), 0, stream>>>(qh, kh, p);
    apply_mfma_kernel<<<dim3(4096), dim3(256), 0, stream>>>(xt, p, w3, b3, out);
  } else {
    float* wsf = (float*)d_ws;
    float* q  = wsf;
    float* k  = wsf + 4194304;
    float* at = wsf + 8388608;
    qk_kernel<<<dim3(16384), dim3(256), 0, stream>>>(x, w1, b1, w2, b2, q, k);
    scores_kernel<<<dim3(2, 2, 64), dim3(256), 0, stream>>>(q, k, at);
    softmax_kernel<<<dim3(4096), dim3(256), 0, stream>>>(at);
    apply_kernel<<<dim3(16, 64), dim3(256), 0, stream>>>(x, at, w3, b3, out);
  }
}

// Round 3
// 308.895 us; speedup vs baseline: 1.6932x; 1.2639x over previous
//
#include <hip/hip_runtime.h>

typedef _Float16 h16;
typedef __attribute__((ext_vector_type(2))) _Float16 half2v;
typedef __attribute__((ext_vector_type(4))) _Float16 half4;
typedef __attribute__((ext_vector_type(8))) _Float16 half8;
typedef __attribute__((ext_vector_type(4))) float f32x4;

#define Cn 8
#define HWn 65536
#define CHWn 524288

// ================================================================ FAST PATH
// ---------------------------------------------------------------- K1: prep
// Reads x once. Produces qh,kh fp16 [b][i][w] and vt fp16 [b][c][w][j] where
// v = w3·x + b3 (bias folds through softmax since sum_j attn = 1).
// Thread micro-tile 4j x 2w, fp32 accumulators; per-co LDS transpose.
__global__ __launch_bounds__(256) void prep_kernel(
    const float* __restrict__ x, const float* __restrict__ w1, const float* __restrict__ b1,
    const float* __restrict__ w2, const float* __restrict__ b2,
    const float* __restrict__ w3, const float* __restrict__ b3,
    h16* __restrict__ qh, h16* __restrict__ kh, h16* __restrict__ vt) {
  const int jt = blockIdx.x, wt = blockIdx.y, b = blockIdx.z;
  const int j0 = jt * 64, w0 = wt * 32;
  const int t = threadIdx.x;
  const int l = t & 15, jq = t >> 4;   // l -> w pair, jq -> j quad (0..15)
  const int wb = w0 + 2 * l;
  const int jb = j0 + 4 * jq;
  __shared__ h16 lds[32 * 72];

  float qa[4][2], ka[4][2], va[8][4][2];
  const float bb1 = b1[0], bb2 = b2[0];
#pragma unroll
  for (int d = 0; d < 4; d++)
#pragma unroll
    for (int e = 0; e < 2; e++) { qa[d][e] = bb1; ka[d][e] = bb2; }
#pragma unroll
  for (int co = 0; co < 8; co++) {
    float bv = b3[co];
#pragma unroll
    for (int d = 0; d < 4; d++)
#pragma unroll
      for (int e = 0; e < 2; e++) va[co][d][e] = bv;
  }

  for (int ci = 0; ci < Cn; ci++) {
    const float* xp = x + ((size_t)(b * Cn + ci) << 16);
    const float w1c = w1[ci], w2c = w2[ci];
    float w3c[8];
#pragma unroll
    for (int co = 0; co < 8; co++) w3c[co] = w3[co * 8 + ci];
#pragma unroll
    for (int d = 0; d < 4; d++) {
      float2 xv = *(const float2*)&xp[(size_t)(jb + d) * 256 + wb];
      qa[d][0] = fmaf(xv.x, w1c, qa[d][0]); qa[d][1] = fmaf(xv.y, w1c, qa[d][1]);
      ka[d][0] = fmaf(xv.x, w2c, ka[d][0]); ka[d][1] = fmaf(xv.y, w2c, ka[d][1]);
#pragma unroll
      for (int co = 0; co < 8; co++) {
        va[co][d][0] = fmaf(xv.x, w3c[co], va[co][d][0]);
        va[co][d][1] = fmaf(xv.y, w3c[co], va[co][d][1]);
      }
    }
  }
  // q,k stores: half2 per j-row, coalesced across l
#pragma unroll
  for (int d = 0; d < 4; d++) {
    half2v qv = {(h16)qa[d][0], (h16)qa[d][1]};
    half2v kv = {(h16)ka[d][0], (h16)ka[d][1]};
    size_t off = ((size_t)b << 16) + (size_t)(jb + d) * 256 + wb;
    *(half2v*)&qh[off] = qv;
    *(half2v*)&kh[off] = kv;
  }
  // per-co transpose: LDS tile [32 w][64 j] stride 72
  const int rrow = t >> 3;   // 0..31 (w-local)
  const int rch = t & 7;     // j chunk of 8
  for (int co = 0; co < 8; co++) {
#pragma unroll
    for (int e = 0; e < 2; e++) {
      half4 hv = {(h16)va[co][0][e], (h16)va[co][1][e], (h16)va[co][2][e], (h16)va[co][3][e]};
      *(half4*)&lds[(2 * l + e) * 72 + 4 * jq] = hv;
    }
    __syncthreads();
    uint4 pk = *(const uint4*)&lds[rrow * 72 + 8 * rch];
    *(uint4*)&vt[((size_t)(b * Cn + co) * 256 + w0 + rrow) * 256 + j0 + 8 * rch] = pk;
    __syncthreads();
  }
}

// ---------------------------------------------------------------- K2: scores + softmax
// Block = 16 i-rows; 4 waves split j (64 each). mfma(K,Q): lane holds col i=lane&15,
// rows j = jt*16 + quad*4 + r. Cross-wave softmax via LDS. P stored fp16 [b][i][j].
__global__ __launch_bounds__(256) void scores_kernel(
    const h16* __restrict__ qh, const h16* __restrict__ kh, h16* __restrict__ p) {
  const int i0 = blockIdx.x * 16, b = blockIdx.y;
  const int t = threadIdx.x, wv = t >> 6, lane = t & 63;
  const int m = lane & 15, quad = lane >> 4;
  __shared__ float red[2][4][16];
  const h16* qrow = qh + ((size_t)b << 16) + (size_t)(i0 + m) * 256 + quad * 8;
  const h16* kbase = kh + ((size_t)b << 16) + (size_t)(wv * 64 + m) * 256 + quad * 8;
  f32x4 acc[4];
#pragma unroll
  for (int jt = 0; jt < 4; jt++) acc[jt] = {0.f, 0.f, 0.f, 0.f};
#pragma unroll
  for (int s = 0; s < 8; s++) {
    half8 Q = *(const half8*)(qrow + s * 32);
#pragma unroll
    for (int jt = 0; jt < 4; jt++) {
      half8 K = *(const half8*)(kbase + (size_t)jt * 4096 + s * 32);
      acc[jt] = __builtin_amdgcn_mfma_f32_16x16x32_f16(K, Q, acc[jt], 0, 0, 0);
    }
  }
  float mx = -3.4e38f;
#pragma unroll
  for (int jt = 0; jt < 4; jt++)
#pragma unroll
    for (int r = 0; r < 4; r++) mx = fmaxf(mx, acc[jt][r]);
  mx = fmaxf(mx, __shfl_xor(mx, 16, 64));
  mx = fmaxf(mx, __shfl_xor(mx, 32, 64));
  if (lane < 16) red[0][wv][lane] = mx;
  __syncthreads();
  float gmx = fmaxf(fmaxf(red[0][0][m], red[0][1][m]), fmaxf(red[0][2][m], red[0][3][m]));
  float sum = 0.f;
#pragma unroll
  for (int jt = 0; jt < 4; jt++)
#pragma unroll
    for (int r = 0; r < 4; r++) {
      float e = __expf(acc[jt][r] - gmx);
      acc[jt][r] = e;
      sum += e;
    }
  sum += __shfl_xor(sum, 16, 64);
  sum += __shfl_xor(sum, 32, 64);
  if (lane < 16) red[1][wv][lane] = sum;
  __syncthreads();
  const float inv = 1.f / (red[1][0][m] + red[1][1][m] + red[1][2][m] + red[1][3][m]);
  h16* pb = p + ((size_t)b << 16) + (size_t)(i0 + m) * 256;
#pragma unroll
  for (int jt = 0; jt < 4; jt++) {
    half4 pv = {(h16)(acc[jt][0] * inv), (h16)(acc[jt][1] * inv),
                (h16)(acc[jt][2] * inv), (h16)(acc[jt][3] * inv)};
    *(half4*)&pb[wv * 64 + jt * 16 + quad * 4] = pv;
  }
}

// ---------------------------------------------------------------- K3: apply = pure GEMM per batch
// C[256 i x 2048 n] = P (256x256) * vt^T (2048x256), n = c*256+w. 128x128 block tile,
// BK=32, LDS padded stride 40 (<=2-way), register prefetch across barrier.
// Wave = 64x64 (4x4 tiles of 16x16x32). Epilogue: direct coalesced store to out.
__global__ __launch_bounds__(256) void apply_kernel_mfma(
    const h16* __restrict__ p, const h16* __restrict__ vt, float* __restrict__ out) {
  const int bx = blockIdx.x, b = blockIdx.y;
  const int it = bx >> 4, nt = bx & 15;
  const int i0 = it * 128, n0 = nt * 128;
  const int t = threadIdx.x, wv = t >> 6, lane = t & 63;
  const int m = lane & 15, quad = lane >> 4;
  const int wy = wv >> 1, wx = wv & 1;
  __shared__ h16 As[128 * 40];
  __shared__ h16 Bs[128 * 40];
  const int srow = t >> 2, soff = (t & 3) * 8;
  const h16* gA = p + ((size_t)b << 16) + (size_t)(i0 + srow) * 256 + soff;
  const h16* gB = vt + (size_t)(b * 2048 + n0 + srow) * 256 + soff;
  uint4 ra0 = *(const uint4*)gA;
  uint4 ra1 = *(const uint4*)(gA + 64 * 256);
  uint4 rb0 = *(const uint4*)gB;
  uint4 rb1 = *(const uint4*)(gB + 64 * 256);
  f32x4 acc[4][4];
#pragma unroll
  for (int ai = 0; ai < 4; ai++)
#pragma unroll
    for (int bi = 0; bi < 4; bi++) acc[ai][bi] = {0.f, 0.f, 0.f, 0.f};
  const int lA = srow * 40 + soff;
  for (int kc = 0; kc < 8; kc++) {
    __syncthreads();
    *(uint4*)&As[lA] = ra0; *(uint4*)&As[lA + 64 * 40] = ra1;
    *(uint4*)&Bs[lA] = rb0; *(uint4*)&Bs[lA + 64 * 40] = rb1;
    __syncthreads();
    if (kc < 7) {
      const int ko = (kc + 1) * 32;
      ra0 = *(const uint4*)(gA + ko);
      ra1 = *(const uint4*)(gA + 64 * 256 + ko);
      rb0 = *(const uint4*)(gB + ko);
      rb1 = *(const uint4*)(gB + 64 * 256 + ko);
    }
    half8 af[4], bf[4];
#pragma unroll
    for (int ai = 0; ai < 4; ai++)
      af[ai] = *(const half8*)&As[(wy * 64 + ai * 16 + m) * 40 + quad * 8];
#pragma unroll
    for (int bi = 0; bi < 4; bi++)
      bf[bi] = *(const half8*)&Bs[(wx * 64 + bi * 16 + m) * 40 + quad * 8];
#pragma unroll
    for (int ai = 0; ai < 4; ai++)
#pragma unroll
      for (int bi = 0; bi < 4; bi++)
        acc[ai][bi] = __builtin_amdgcn_mfma_f32_16x16x32_f16(af[ai], bf[bi], acc[ai][bi], 0, 0, 0);
  }
  const int c = nt >> 1;
  const int wcol0 = (nt & 1) * 128 + wx * 64;
  float* ob = out + ((size_t)(b * Cn + c) << 16);
#pragma unroll
  for (int ai = 0; ai < 4; ai++) {
    const int ib = i0 + wy * 64 + ai * 16 + quad * 4;
#pragma unroll
    for (int r = 0; r < 4; r++)
#pragma unroll
      for (int bi = 0; bi < 4; bi++)
        ob[(size_t)(ib + r) * 256 + wcol0 + bi * 16 + m] = acc[ai][bi][r];
  }
}

// ================================================================ FALLBACK (fp32, R1-proven)
__global__ __launch_bounds__(256) void qk_kernel(
    const float* __restrict__ x, const float* __restrict__ w1, const float* __restrict__ b1,
    const float* __restrict__ w2, const float* __restrict__ b2,
    float* __restrict__ q, float* __restrict__ k) {
  int n = blockIdx.x * 256 + threadIdx.x;
  int b = n >> 16;
  int pidx = n & 65535;
  const float* xb = x + (size_t)b * CHWn + pidx;
  float qa = b1[0], ka = b2[0];
#pragma unroll
  for (int c = 0; c < Cn; c++) {
    float xv = xb[c * HWn];
    qa = fmaf(xv, w1[c], qa);
    ka = fmaf(xv, w2[c], ka);
  }
  q[n] = qa;
  k[n] = ka;
}

__global__ __launch_bounds__(256) void scores_kernel_f32(
    const float* __restrict__ q, const float* __restrict__ k, float* __restrict__ sc) {
  const int jt = blockIdx.x, it = blockIdx.y, b = blockIdx.z;
  const int i0 = it * 128, j0 = jt * 128;
  const int t = threadIdx.x;
  const int tx = t & 15, ty = t >> 4;
  __shared__ __align__(16) float qt[32 * 132];
  __shared__ __align__(16) float kt[32 * 132];
  float acc[2][2][4][4];
#pragma unroll
  for (int a = 0; a < 2; a++)
#pragma unroll
    for (int bb = 0; bb < 2; bb++)
#pragma unroll
      for (int il = 0; il < 4; il++)
#pragma unroll
        for (int jl = 0; jl < 4; jl++) acc[a][bb][il][jl] = 0.f;
  const float* qb = q + (size_t)b * HWn;
  const float* kb = k + (size_t)b * HWn;
  for (int kc = 0; kc < 8; kc++) {
    const int w0 = kc * 32;
    __syncthreads();
#pragma unroll
    for (int e = 0; e < 16; e++) {
      int idx = t + 256 * e;
      int r = idx >> 5, c = idx & 31;
      qt[c * 132 + r] = qb[(i0 + r) * 256 + w0 + c];
      kt[c * 132 + r] = kb[(j0 + r) * 256 + w0 + c];
    }
    __syncthreads();
#pragma unroll 4
    for (int w = 0; w < 32; w++) {
      const float4 a0 = *(const float4*)&qt[w * 132 + ty * 4];
      const float4 a1 = *(const float4*)&qt[w * 132 + 64 + ty * 4];
      const float4 b0 = *(const float4*)&kt[w * 132 + tx * 4];
      const float4 b1 = *(const float4*)&kt[w * 132 + 64 + tx * 4];
      const float av[2][4] = {{a0.x, a0.y, a0.z, a0.w}, {a1.x, a1.y, a1.z, a1.w}};
      const float bv[2][4] = {{b0.x, b0.y, b0.z, b0.w}, {b1.x, b1.y, b1.z, b1.w}};
#pragma unroll
      for (int ih = 0; ih < 2; ih++)
#pragma unroll
        for (int jh = 0; jh < 2; jh++)
#pragma unroll
          for (int il = 0; il < 4; il++)
#pragma unroll
            for (int jl = 0; jl < 4; jl++)
              acc[ih][jh][il][jl] = fmaf(av[ih][il], bv[jh][jl], acc[ih][jh][il][jl]);
    }
  }
  float* scb = sc + (size_t)b * HWn;
#pragma unroll
  for (int ih = 0; ih < 2; ih++)
#pragma unroll
    for (int il = 0; il < 4; il++) {
      int i = i0 + ih * 64 + ty * 4 + il;
#pragma unroll
      for (int jh = 0; jh < 2; jh++) {
        float4 st = make_float4(acc[ih][jh][il][0], acc[ih][jh][il][1],
                                acc[ih][jh][il][2], acc[ih][jh][il][3]);
        *(float4*)&scb[i * 256 + j0 + jh * 64 + tx * 4] = st;
      }
    }
}

__global__ __launch_bounds__(256) void softmax_kernel(float* __restrict__ at) {
  int wave = (blockIdx.x * 256 + threadIdx.x) >> 6;
  int lane = threadIdx.x & 63;
  float* row = at + (size_t)wave * 256;
  float v[4];
  float mm = -3.4e38f;
#pragma unroll
  for (int u = 0; u < 4; u++) {
    v[u] = row[lane + 64 * u];
    mm = fmaxf(mm, v[u]);
  }
#pragma unroll
  for (int o = 1; o < 64; o <<= 1) mm = fmaxf(mm, __shfl_xor(mm, o, 64));
  float s = 0.f;
#pragma unroll
  for (int u = 0; u < 4; u++) {
    v[u] = __expf(v[u] - mm);
    s += v[u];
  }
#pragma unroll
  for (int o = 1; o < 64; o <<= 1) s += __shfl_xor(s, o, 64);
  float inv = 1.0f / s;
#pragma unroll
  for (int u = 0; u < 4; u++) row[lane + 64 * u] = v[u] * inv;
}

__global__ __launch_bounds__(256, 2) void apply_kernel(
    const float* __restrict__ x, const float* __restrict__ at,
    const float* __restrict__ w3, const float* __restrict__ b3, float* __restrict__ out) {
  const int it = blockIdx.x, b = blockIdx.y;
  const int i0 = it * 16;
  const int t = threadIdx.x;
  __shared__ __align__(16) float pt[16 * 256];
  const float* atb = at + (size_t)b * HWn + i0 * 256;
#pragma unroll
  for (int e = 0; e < 4; e++)
    *(float4*)&pt[t * 4 + 1024 * e] = *(const float4*)&atb[t * 4 + 1024 * e];
  __syncthreads();
  float acc[8][16];
#pragma unroll
  for (int c = 0; c < 8; c++)
#pragma unroll
    for (int ii = 0; ii < 16; ii++) acc[c][ii] = 0.f;
  const float* xb = x + (size_t)b * CHWn + t;
  for (int j0 = 0; j0 < 256; j0 += 2) {
    float p2[16][2];
#pragma unroll
    for (int ii = 0; ii < 16; ii++) {
      float2 pp = *(const float2*)&pt[ii * 256 + j0];
      p2[ii][0] = pp.x;
      p2[ii][1] = pp.y;
    }
#pragma unroll
    for (int ju = 0; ju < 2; ju++) {
      float xv[8];
#pragma unroll
      for (int c = 0; c < 8; c++) xv[c] = xb[c * HWn + (j0 + ju) * 256];
#pragma unroll
      for (int c = 0; c < 8; c++)
#pragma unroll
        for (int ii = 0; ii < 16; ii++)
          acc[c][ii] = fmaf(xv[c], p2[ii][ju], acc[c][ii]);
    }
  }
#pragma unroll
  for (int co = 0; co < 8; co++) {
    float wr[8];
#pragma unroll
    for (int ci = 0; ci < 8; ci++) wr[ci] = w3[co * 8 + ci];
    float bb = b3[co];
#pragma unroll
    for (int ii = 0; ii < 16; ii++) {
      float o = bb;
#pragma unroll
      for (int ci = 0; ci < 8; ci++) o = fmaf(wr[ci], acc[ci][ii], o);
      out[(size_t)b * CHWn + co * HWn + (i0 + ii) * 256 + t] = o;
    }
  }
}

extern "C" void kernel_launch(void* const* d_in, const int* in_sizes, int n_in,
                              void* d_out, int out_size, void* d_ws, size_t ws_size,
                              hipStream_t stream) {
  const float* x  = (const float*)d_in[0];
  const float* w1 = (const float*)d_in[1];
  const float* b1 = (const float*)d_in[2];
  const float* w2 = (const float*)d_in[3];
  const float* b2 = (const float*)d_in[4];
  const float* w3 = (const float*)d_in[5];
  const float* b3 = (const float*)d_in[6];
  float* out = (float*)d_out;

  if (ws_size >= (size_t)92274688) {
    // fast path: vt 64MB | qh 8MB | kh 8MB | p 8MB
    char* wsb = (char*)d_ws;
    h16* vt = (h16*)wsb;
    h16* qh = (h16*)(wsb + 67108864);
    h16* kh = (h16*)(wsb + 75497472);
    h16* p  = (h16*)(wsb + 83886080);
    prep_kernel<<<dim3(4, 8, 64), dim3(256), 0, stream>>>(x, w1, b1, w2, b2, w3, b3, qh, kh, vt);
    scores_kernel<<<dim3(16, 64), dim3(256), 0, stream>>>(qh, kh, p);
    apply_kernel_mfma<<<dim3(32, 64), dim3(256), 0, stream>>>(p, vt, out);
  } else {
    float* wsf = (float*)d_ws;
    float* q  = wsf;
    float* k  = wsf + 4194304;
    float* at = wsf + 8388608;
    qk_kernel<<<dim3(16384), dim3(256), 0, stream>>>(x, w1, b1, w2, b2, q, k);
    scores_kernel_f32<<<dim3(2, 2, 64), dim3(256), 0, stream>>>(q, k, at);
    softmax_kernel<<<dim3(4096), dim3(256), 0, stream>>>(at);
    apply_kernel<<<dim3(16, 64), dim3(256), 0, stream>>>(x, at, w3, b3, out);
  }
}